// Round 12
// baseline (176.946 us; speedup 1.0000x reference)
//
#include <hip/hip_runtime.h>
#include <math.h>

#define JT 64                // j per block (register-resident, 1 per lane)
#define ITILE 1024           // i per block (uniform-iterated, 256 per wave)
#define T8 8                 // 1024-tiles per dimension
#define NJOB_AB 1024         // 8 i-tiles * 128 j-chunks
#define NJOB_TRI 576         // 36 tri-tiles * 16 chunks
#define NBLK (NJOB_AB + 2 * NJOB_TRI)  // 2176
#define L2E 1.4426950408889634f

__device__ inline float fexp2(float x) {  // exp2(x), one instruction
  float r;
  asm("v_exp_f32 %0, %1" : "=v"(r) : "v"(x));
  return r;
}
__device__ inline float fsqrt(float x) {
  float r;
  asm("v_sqrt_f32 %0, %1" : "=v"(r) : "v"(x));
  return r;
}

__device__ inline double wred_d(double v) {
#pragma unroll
  for (int o = 32; o > 0; o >>= 1) v += __shfl_down(v, o, 64);
  return v;
}

__device__ inline double bred(double v, double* sm) {
  v = wred_d(v);
  __syncthreads();
  if ((threadIdx.x & 63) == 0) sm[threadIdx.x >> 6] = v;
  __syncthreads();
  return sm[0] + sm[1] + sm[2] + sm[3];
}

// wave 0: reduce 64 prep slots (stride 8, 7 channels) ->
// smean[0..6]=base {Su,Suu,Sux,Suy,Sx,Sy,Sq}, smean[8..14]=target
__device__ inline void slot_reduce(const double* slot, double* smean) {
  if (threadIdx.x < 64) {
    int l = threadIdx.x;
    const double* sl = slot + l * 8;
#pragma unroll
    for (int c = 0; c < 7; ++c) {
      double v = sl[c];
      double vb = (l < 32) ? v : 0.0;
      double vt = (l < 32) ? 0.0 : v;
      vb = wred_d(vb);
      vt = wred_d(vt);
      if (l == 0) {
        smean[c] = vb;
        smean[8 + c] = vt;
      }
    }
  }
}

__global__ __launch_bounds__(256) void prep_kernel(
    const float* __restrict__ base, const float* __restrict__ target,
    const float* __restrict__ log_sigmas, const float* __restrict__ log_scale,
    const float* __restrict__ w1, const float* __restrict__ b1,
    const float* __restrict__ w2, const float* __restrict__ b2,
    float4* __restrict__ pxyu, double* __restrict__ slot,
    unsigned* __restrict__ fctr, int n) {
  __shared__ double sm[4];
  int gid = blockIdx.x * 256 + threadIdx.x;
  int isT = gid >= n;  // uniform per block (n % 256 == 0)
  const float* pts = isT ? target : base;
  int idx = isT ? gid - n : gid;
  float ex = __expf(log_scale[0]);
  float ey = __expf(log_scale[1]);
  float s2 = __expf(log_sigmas[2]);
  float r2 = __fsqrt_rn(L2E / (2.f * s2 * s2));  // coord pre-scale, band 2
  float2 p = ((const float2*)pts)[idx];
  float xr = p.x * ex, yr = p.y * ey;  // MLP input space (no r2!)
  float logit = b2[0];
#pragma unroll
  for (int k = 0; k < 32; ++k) {
    float h = fmaf(xr, w1[k], fmaf(yr, w1[32 + k], b1[k]));
    h = fmaxf(h, 0.f);
    logit = fmaf(h, w2[k], logit);
  }
  float u = fmaxf(logit, 0.f) + log1pf(__expf(-fabsf(logit))) + 1e-6f;
  float X = xr * r2, Y = yr * r2;
  float q = fmaf(X, X, Y * Y);  // |P|^2 (scaled)
  pxyu[gid] = make_float4(X, Y, -q, u);  // NEGATED q: inner loop wants -|P|^2
  double su = bred((double)u, sm);
  double qu = bred((double)u * (double)u, sm);
  double mx = bred((double)u * (double)X, sm);
  double my = bred((double)u * (double)Y, sm);
  double sx = bred((double)X, sm);
  double sy = bred((double)Y, sm);
  double sq = bred((double)q, sm);
  if (threadIdx.x == 0) {
    double* s = slot + blockIdx.x * 8;
    s[0] = su;
    s[1] = qu;
    s[2] = mx;
    s[3] = my;
    s[4] = sx;
    s[5] = sy;
    s[6] = sq;
    if (blockIdx.x == 0) *fctr = 0u;
  }
}

// Inner loop: j in per-lane registers; i streamed via wave-uniform loads
// (ibase proved uniform -> s_load on the scalar pipe, zero VALU issue).
// narg = -(pos_raw); karg = -(pos_centered) for AB.
template <bool AB, bool FAST>
__device__ inline void iloop(const float4* __restrict__ pI, int ibase,
                             float xj2, float yj2, float mqj, float nhj,
                             float cx2, float cy2, float cc, float rr0,
                             float rr1, float a[3], float& sd) {
#pragma unroll 8
  for (int ii = 0; ii < ITILE / 4; ++ii) {
    float4 I = pI[ibase + ii];  // wave-uniform -> s_load_dwordx4
    float t = fmaf(I.y, yj2, mqj);
    float narg = fmaf(I.x, xj2, t) + I.z;  // = -(pos_raw) (I.z = -qi)
    float karg;
    if constexpr (AB) {
      float ngi = fmaf(cx2, I.x, fmaf(cy2, I.y, -cc));  // = -(cc - 2c.pi)
      karg = (narg + ngi) + nhj;                        // = -(pos_centered)
    } else {
      karg = narg;
    }
    float k2 = fexp2(karg);
    float k0, k1;
    if constexpr (FAST) {
      float t2 = k2 * k2;
      k1 = t2 * t2;  // k2^4  (sigma 1:2)
      float t4 = k1 * k1;
      k0 = t4 * t4;  // k2^16 (sigma 1:4)
    } else {
      k1 = fexp2(karg * rr1);
      k0 = fexp2(karg * rr0);
    }
    a[0] = fmaf(I.w, k0, a[0]);  // u_i folded; u_j applied at block end
    a[1] = fmaf(I.w, k1, a[1]);
    a[2] = fmaf(I.w, k2, a[2]);
    if constexpr (AB) {
      float d2u = fmaxf(-narg, 0.f);  // uncentered scaled d2, clamped
      sd += fsqrt(d2u);
    }
  }
}

__global__ __launch_bounds__(256) void pair_kernel(
    const float4* __restrict__ pxyu, const double* __restrict__ slot,
    double* __restrict__ paa, double* __restrict__ pbb,
    double* __restrict__ pab, double* __restrict__ psd,
    unsigned* __restrict__ fctr, const float* __restrict__ log_sigmas,
    const float* __restrict__ g_w1, const float* __restrict__ g_b1,
    const float* __restrict__ g_w2, const float* __restrict__ g_b2,
    const float* __restrict__ bias, float* __restrict__ out, int n) {
  __shared__ double sm[4];
  __shared__ double smean[16];
  __shared__ int lastf;

  int b = blockIdx.x;
  int tid = threadIdx.x;
  int m, it, jt = 0, j0, pidx;
  if (b < NJOB_AB) {  // AB first (heavier), light tri jobs drain last
    m = 2;
    pidx = b;
    it = b >> 7;          // 8 i-tiles
    j0 = (b & 127) * JT;  // 128 j-chunks
  } else {
    int r = b - NJOB_AB;
    m = (r < NJOB_TRI) ? 0 : 1;
    if (m == 1) r -= NJOB_TRI;
    pidx = r;
    int tile = r >> 4;
    int q = r & 15;
    int idx = tile, len = T8;
    it = 0;
    while (idx >= len) {
      idx -= len;
      --len;
      ++it;
    }
    jt = it + idx;
    j0 = jt * ITILE + q * JT;
  }
  const float4* pI = pxyu + ((m == 1) ? n : 0);
  const float4* pJ = pxyu + ((m == 0) ? 0 : n);

  if (m == 2) {
    slot_reduce(slot, smean);  // wave 0; consumed after the barrier below
  }

  float s0 = __expf(log_sigmas[0]);
  float s1 = __expf(log_sigmas[1]);
  float s2 = __expf(log_sigmas[2]);
  float rr0 = (s2 * s2) / (s0 * s0);
  float rr1 = (s2 * s2) / (s1 * s1);
  bool fast = (fabsf(rr0 - 16.f) <= 0.016f) && (fabsf(rr1 - 4.f) <= 0.004f);

  float cx2 = 0.f, cy2 = 0.f, cc = 0.f;
  if (m == 2) {
    __syncthreads();
    float cx = (float)(smean[2] / smean[0] - smean[10] / smean[8]);
    float cy = (float)(smean[3] / smean[0] - smean[11] / smean[8]);
    cx2 = 2.f * cx;
    cy2 = 2.f * cy;
    cc = cx * cx + cy * cy;
  }

  // ---- per-lane j point (register resident for the whole block) ----
  float4 J = pJ[j0 + (tid & 63)];
  float xj2 = J.x + J.x;
  float yj2 = J.y + J.y;
  float mqj = J.z;  // = -|pj|^2
  float uj = J.w;
  float nhj = 0.f;
  if (m == 2) nhj = -fmaf(cx2, J.x, cy2 * J.y);  // = -(2c.pj)

  int wid = __builtin_amdgcn_readfirstlane(tid >> 6);  // provably uniform
  int ibase = it * ITILE + wid * (ITILE / 4);

  float a[3] = {0.f, 0.f, 0.f};
  float sd = 0.f;
  if (m == 2) {
    if (fast)
      iloop<true, true>(pI, ibase, xj2, yj2, mqj, nhj, cx2, cy2, cc, rr0, rr1,
                        a, sd);
    else
      iloop<true, false>(pI, ibase, xj2, yj2, mqj, nhj, cx2, cy2, cc, rr0,
                         rr1, a, sd);
  } else {
    if (fast)
      iloop<false, true>(pI, ibase, xj2, yj2, mqj, nhj, cx2, cy2, cc, rr0,
                         rr1, a, sd);
    else
      iloop<false, false>(pI, ibase, xj2, yj2, mqj, nhj, cx2, cy2, cc, rr0,
                          rr1, a, sd);
  }

  double wgt = (m != 2 && jt != it) ? 2.0 : 1.0;  // symmetric off-diag tiles
  double r0 = bred((double)(uj * a[0]), sm) * wgt;
  double r1 = bred((double)(uj * a[1]), sm) * wgt;
  double r2d = bred((double)(uj * a[2]), sm) * wgt;
  double* prow = (m == 0) ? paa : (m == 1) ? pbb : pab;
  int stride = (m == 2) ? NJOB_AB : NJOB_TRI;
  if (tid == 0) {
    prow[0 * stride + pidx] = r0;
    prow[1 * stride + pidx] = r1;
    prow[2 * stride + pidx] = r2d;
  }
  if (m == 2) {
    double rsd = bred((double)sd, sm);
    if (tid == 0) psd[pidx] = rsd;
  }

  // ---- last-block final reduction (ticket + device fence) ----
  if (tid == 0) {
    __threadfence();
    unsigned old = atomicAdd(fctr, 1u);
    lastf = (old == NBLK - 1) ? 1 : 0;
  }
  __syncthreads();
  if (!lastf) return;
  __threadfence();

  slot_reduce(slot, smean);
  __syncthreads();
  int t = tid;
  double vaa[3], vbb[3], vab[3];
  for (int s = 0; s < 3; ++s) {
    const double* pa = paa + s * NJOB_TRI;
    const double* pb = pbb + s * NJOB_TRI;
    const double* pc = pab + s * NJOB_AB;
    double va = pa[t] + pa[t + 256] + ((t < 64) ? pa[t + 512] : 0.0);
    double vb = pb[t] + pb[t + 256] + ((t < 64) ? pb[t + 512] : 0.0);
    double vc = pc[t] + pc[t + 256] + pc[t + 512] + pc[t + 768];
    vaa[s] = bred(va, sm);
    vbb[s] = bred(vb, sm);
    vab[s] = bred(vc, sm);
  }
  double sdt = bred(psd[t] + psd[t + 256] + psd[t + 512] + psd[t + 768], sm);

  if (tid == 0) {
    double Sb = smean[0], Qb = smean[1], St = smean[8], Qt = smean[9];
    double SxB = smean[4], SyB = smean[5], SqB = smean[6];
    double SxT = smean[12], SyT = smean[13], SqT = smean[14];
    double pband[3];
    for (int s = 0; s < 3; ++s)
      pband[s] = vaa[s] / (Sb * Sb) + vbb[s] / (St * St) -
                 2.0 * vab[s] / (Sb * St);
    double s2d = (double)s2;
    double r2sq = (double)L2E / (2.0 * s2d * s2d);
    double NN = (double)n;
    // closed-form Sum d2 (scaled): N*(SqB+SqT) - 2*(SxB*SxT + SyB*SyT)
    double sq_scaled = NN * (SqB + SqT) - 2.0 * (SxB * SxT + SyB * SyT);
    double sd_real = sdt / sqrt(r2sq);
    double sq_real = sq_scaled / r2sq;
    double NM = NN * NN;
    double mean_d = sd_real / NM;
    double var_d = (sq_real - sd_real * sd_real / NM) / (NM - 1.0);
    double wv = (Qb / (Sb * Sb) - 1.0 / NN) / (NN - 1.0) +
                (Qt / (St * St) - 1.0 / NN) / (NN - 1.0);
    float st[4] = {(float)mean_d, (float)var_d, 0.f, (float)wv};
    float gl[3] = {g_b2[0], g_b2[1], g_b2[2]};
    for (int k = 0; k < 32; ++k) {
      float h = g_b1[k];
      for (int c = 0; c < 4; ++c) h = fmaf(st[c], g_w1[c * 32 + k], h);
      h = fmaxf(h, 0.f);
      for (int s = 0; s < 3; ++s) gl[s] = fmaf(h, g_w2[k * 3 + s], gl[s]);
    }
    float gw[3];
    float gsum = 0.f;
    for (int s = 0; s < 3; ++s) {
      gw[s] = fmaxf(gl[s], 0.f) + log1pf(__expf(-fabsf(gl[s])));
      gsum += gw[s];
    }
    double r = 0.0;
    for (int s = 0; s < 3; ++s) r += (double)(gw[s] / gsum) * pband[s];
    out[0] = (float)(r + (double)bias[0]);
  }
}

extern "C" void kernel_launch(void* const* d_in, const int* in_sizes, int n_in,
                              void* d_out, int out_size, void* d_ws,
                              size_t ws_size, hipStream_t stream) {
  const float* base = (const float*)d_in[0];
  const float* target = (const float*)d_in[1];
  const float* log_sigmas = (const float*)d_in[2];
  const float* log_scale = (const float*)d_in[3];
  const float* wn_w1 = (const float*)d_in[4];
  const float* wn_b1 = (const float*)d_in[5];
  const float* wn_w2 = (const float*)d_in[6];
  const float* wn_b2 = (const float*)d_in[7];
  const float* g_w1 = (const float*)d_in[8];
  const float* g_b1 = (const float*)d_in[9];
  const float* g_w2 = (const float*)d_in[10];
  const float* g_b2 = (const float*)d_in[11];
  const float* bias = (const float*)d_in[12];
  int n = in_sizes[0] / 2;  // 8192

  double* dbase = (double*)d_ws;
  double* slot = dbase;                // 64*8 = 512
  double* paa = dbase + 512;           // 3*576
  double* pbb = paa + 3 * NJOB_TRI;    // 3*576
  double* pab = pbb + 3 * NJOB_TRI;    // 3*1024
  double* psd = pab + 3 * NJOB_AB;     // 1024
  double* dend = psd + NJOB_AB;        // 16B-aligned
  float4* pxyu = (float4*)dend;        // 2n
  unsigned* fctr = (unsigned*)(pxyu + 2 * n);

  prep_kernel<<<(2 * n) / 256, 256, 0, stream>>>(
      base, target, log_sigmas, log_scale, wn_w1, wn_b1, wn_w2, wn_b2, pxyu,
      slot, fctr, n);
  pair_kernel<<<NBLK, 256, 0, stream>>>(pxyu, slot, paa, pbb, pab, psd, fctr,
                                        log_sigmas, g_w1, g_b1, g_w2, g_b2,
                                        bias, (float*)d_out, n);
}